// Round 1
// baseline (173.610 us; speedup 1.0000x reference)
//
#include <hip/hip_runtime.h>
#include <stdint.h>

#define MAX_TRIALS 50
#define MARGIN 1.0f

// ---------------- JAX threefry2x32, key = jax.random.key(42) = [0, 42] -----
__device__ __forceinline__ uint32_t rotl32(uint32_t x, uint32_t d) {
  return (x << d) | (x >> (32u - d));
}

// Returns output `which` (0 or 1) of threefry2x32 with key (0,42) on (x0,x1).
__device__ __forceinline__ uint32_t threefry_0_42(uint32_t x0, uint32_t x1, int which) {
  const uint32_t k0 = 0u, k1 = 42u;
  const uint32_t k2 = k0 ^ k1 ^ 0x1BD11BDAu;
  const uint32_t ks[3] = {k0, k1, k2};
  const uint32_t rotA[4] = {13u, 15u, 26u, 6u};
  const uint32_t rotB[4] = {17u, 29u, 16u, 24u};
  x0 += ks[0];
  x1 += ks[1];
#pragma unroll
  for (int r = 0; r < 5; ++r) {
#pragma unroll
    for (int j = 0; j < 4; ++j) {
      uint32_t rot = (r & 1) ? rotB[j] : rotA[j];
      x0 += x1;
      x1 = rotl32(x1, rot);
      x1 ^= x0;
    }
    x0 += ks[(r + 1) % 3];
    x1 += ks[(r + 2) % 3] + (uint32_t)(r + 1);
  }
  return which ? x1 : x0;
}

// ---------------- K1: per-block count of label==0 --------------------------
__global__ void __launch_bounds__(256) count_kernel(const int* __restrict__ labels,
                                                    int* __restrict__ blockCounts, int B) {
  int gid = blockIdx.x * 256 + threadIdx.x;
  bool isNeg = (gid < B) && (labels[gid] == 0);
  unsigned long long m = __ballot(isNeg);
  __shared__ int wc[4];
  int lane = threadIdx.x & 63, wave = threadIdx.x >> 6;
  if (lane == 0) wc[wave] = __popcll(m);
  __syncthreads();
  if (threadIdx.x == 0) blockCounts[blockIdx.x] = wc[0] + wc[1] + wc[2] + wc[3];
}

// ---------------- K2: single-block exclusive scan of block counts ----------
__global__ void __launch_bounds__(256) scan_kernel(const int* __restrict__ blockCounts,
                                                   int* __restrict__ blockOffsets,
                                                   int* __restrict__ counters,
                                                   float* __restrict__ total, int nblocks) {
  __shared__ int sums[256];
  __shared__ int offs[256];
  int t = threadIdx.x;
  int per = (nblocks + 255) / 256;
  int base = t * per;
  int s = 0;
  for (int k = 0; k < per; ++k) {
    int i = base + k;
    if (i < nblocks) s += blockCounts[i];
  }
  sums[t] = s;
  __syncthreads();
  if (t == 0) {
    int acc = 0;
    for (int k = 0; k < 256; ++k) {
      offs[k] = acc;
      acc += sums[k];
    }
    counters[0] = acc;  // num_neg
    total[0] = 0.0f;    // zero the loss accumulator (ws is poisoned each call)
  }
  __syncthreads();
  int acc = offs[t];
  for (int k = 0; k < per; ++k) {
    int i = base + k;
    if (i < nblocks) {
      blockOffsets[i] = acc;
      acc += blockCounts[i];
    }
  }
}

// ---------------- K3: stable scatter of negative indices -------------------
__global__ void __launch_bounds__(256) scatter_kernel(const int* __restrict__ labels,
                                                      const int* __restrict__ blockOffsets,
                                                      int* __restrict__ negOrder, int B) {
  int gid = blockIdx.x * 256 + threadIdx.x;
  bool isNeg = (gid < B) && (labels[gid] == 0);
  unsigned long long m = __ballot(isNeg);
  int lane = threadIdx.x & 63, wave = threadIdx.x >> 6;
  __shared__ int wc[4];
  if (lane == 0) wc[wave] = __popcll(m);
  __syncthreads();
  int waveOff = 0;
  for (int w = 0; w < wave; ++w) waveOff += wc[w];
  if (isNeg) {
    int lower = __popcll(m & ((1ULL << lane) - 1ULL));
    negOrder[blockOffsets[blockIdx.x] + waveOff + lower] = gid;
  }
}

// ---------------- K4: rejection sampling + weighted hinge, early exit ------
__global__ void __launch_bounds__(256) warp_main(const float* __restrict__ scores,
                                                 const int* __restrict__ labels,
                                                 const int* __restrict__ negOrder,
                                                 const int* __restrict__ counters,
                                                 float* __restrict__ total, int B) {
  int gid = blockIdx.x * 256 + threadIdx.x;
  int num_neg = counters[0];
  float per = 0.0f;
  if (gid < B && num_neg > 0 && labels[gid] == 1) {
    float s = scores[gid];
    float fneg = (float)num_neg;
    uint32_t half = (uint32_t)B * 25u;  // (B*MAX_TRIALS)/2
    uint32_t jbase = (uint32_t)gid * (uint32_t)MAX_TRIALS;
    int trials = -1;
    float neg_at = 0.0f;
    for (int t = 0; t < MAX_TRIALS; ++t) {
      uint32_t j = jbase + (uint32_t)t;
      uint32_t x0, x1;
      int which;
      if (j < half) { x0 = j; x1 = j + half; which = 0; }
      else          { x0 = j - half; x1 = j; which = 1; }
      uint32_t bits = threefry_0_42(x0, x1, which);
      // jax uniform: bitcast((bits>>9) | 0x3f800000) - 1.0
      float u = __uint_as_float((bits >> 9) | 0x3f800000u) - 1.0f;
      int idx = (int)(u * fneg);  // truncation toward zero == astype(int32)
      if (idx > num_neg - 1) idx = num_neg - 1;
      float neg = scores[negOrder[idx]];
      if (neg + MARGIN > s) {  // first violation == argmax(violates)
        trials = t;
        neg_at = neg;
        break;
      }
    }
    if (trials >= 0) {
      int rank = MAX_TRIALS / (trials + 1);
      if (rank < 1) rank = 1;
      // harmonic number H(rank), fp32 sequential cumsum (matches jnp.cumsum)
      float w = 0.0f;
      for (int k = 1; k <= rank; ++k) w += 1.0f / (float)k;
      float h = MARGIN - (s - neg_at);
      if (h < 0.0f) h = 0.0f;
      per = w * h;
    }
  }
  // block reduction: wave shuffle + LDS + one atomic per block
  float v = per;
#pragma unroll
  for (int off = 32; off > 0; off >>= 1) v += __shfl_down(v, off, 64);
  __shared__ float bsum[4];
  int lane = threadIdx.x & 63, wave = threadIdx.x >> 6;
  if (lane == 0) bsum[wave] = v;
  __syncthreads();
  if (threadIdx.x == 0) atomicAdd(total, bsum[0] + bsum[1] + bsum[2] + bsum[3]);
}

// ---------------- K5: finalize ---------------------------------------------
__global__ void finalize_kernel(const float* __restrict__ total,
                                const int* __restrict__ counters,
                                float* __restrict__ out, int B) {
  if (blockIdx.x == 0 && threadIdx.x == 0) {
    int num_neg = counters[0];
    int num_pos = B - num_neg;
    float r = 0.0f;
    if (num_pos > 0 && num_neg > 0) r = total[0] / (float)num_pos;
    out[0] = r;
  }
}

extern "C" void kernel_launch(void* const* d_in, const int* in_sizes, int n_in,
                              void* d_out, int out_size, void* d_ws, size_t ws_size,
                              hipStream_t stream) {
  const float* scores = (const float*)d_in[0];
  const int* labels = (const int*)d_in[1];
  int B = in_sizes[0];
  int nblocks = (B + 255) / 256;

  // workspace layout
  char* ws = (char*)d_ws;
  int* counters = (int*)ws;                 // [0]: num_neg
  float* total = (float*)(ws + 4);          // loss accumulator
  int* blockCounts = (int*)(ws + 64);       // nblocks ints
  int* blockOffsets = blockCounts + nblocks;  // nblocks ints
  int* negOrder = blockOffsets + nblocks;     // B ints (first num_neg used)

  count_kernel<<<nblocks, 256, 0, stream>>>(labels, blockCounts, B);
  scan_kernel<<<1, 256, 0, stream>>>(blockCounts, blockOffsets, counters, total, nblocks);
  scatter_kernel<<<nblocks, 256, 0, stream>>>(labels, blockOffsets, negOrder, B);
  warp_main<<<nblocks, 256, 0, stream>>>(scores, labels, negOrder, counters, total, B);
  finalize_kernel<<<1, 64, 0, stream>>>(total, counters, (float*)d_out, B);
}